// Round 3
// baseline (110.127 us; speedup 1.0000x reference)
//
#include <hip/hip_runtime.h>

// RelativePositionEncoder: out[i,j,:] = W_pos[d_res] + W_tok[d_tok]
//                                      + W_chain[d_chain] + same_entity * w_ent
// B=1, N=1024, TOKEN_Z=128, W is 139x128 f32 (66 pos + 66 tok + 1 ent + 6 chain).
//
// Structure: at most ONE of {d_res, d_tok, d_chain} is non-default per pair:
//   !same_chain            -> d_res=65, d_tok=65, d_chain in 0..4   (5 rows)
//   same_chain & !same_res -> d_tok=65, d_chain=5, d_res  in 0..64  (65 rows)
//   same_chain &  same_res -> d_res=32, d_chain=5, d_tok  in 0..64  (65 rows)
// x2 for same_entity -> 270 distinct combined 128-f32 rows (138 KB).
// Kernel 1 builds the table in d_ws; kernel 2 does 1 gather + 1 store per
// float4 of the 537 MB output (write-BW-bound).

#define N_TOK   1024
#define R_MAX   32
#define S_MAX   2
#define ROW_POS   0
#define ROW_TOK   66
#define ROW_ENT   132
#define ROW_CHAIN 133
#define TBL_BASE  135          // rows per ent-variant
#define TBL_ROWS  270
#define TBL_BYTES (TBL_ROWS * 128 * 4)

__global__ __launch_bounds__(256) void build_table(
    const float* __restrict__ W, float* __restrict__ tbl)
{
    const int t = blockIdx.x * blockDim.x + threadIdx.x;
    if (t >= TBL_ROWS * 32) return;
    const int id   = t >> 5;
    const int slot = t & 31;
    const int ent  = (id >= TBL_BASE) ? 1 : 0;
    const int base = id - ent * TBL_BASE;

    const float4* __restrict__ W4 = (const float4*)W;
    float4 p, k, c;
    if (base < 5) {                       // !same_chain, d_chain = base
        p = W4[(ROW_POS   + 65)   * 32 + slot];
        k = W4[(ROW_TOK   + 65)   * 32 + slot];
        c = W4[(ROW_CHAIN + base) * 32 + slot];
    } else if (base < 70) {               // same_chain & !same_res, d_res = base-5
        p = W4[(ROW_POS + (base - 5)) * 32 + slot];
        k = W4[(ROW_TOK   + 65)   * 32 + slot];
        c = W4[(ROW_CHAIN + 5)    * 32 + slot];
    } else {                              // same_chain & same_res, d_tok = base-70
        p = W4[(ROW_POS   + 32)   * 32 + slot];
        k = W4[(ROW_TOK + (base - 70)) * 32 + slot];
        c = W4[(ROW_CHAIN + 5)    * 32 + slot];
    }
    float4 r;
    r.x = p.x + k.x + c.x;
    r.y = p.y + k.y + c.y;
    r.z = p.z + k.z + c.z;
    r.w = p.w + k.w + c.w;
    if (ent) {
        const float4 e = W4[ROW_ENT * 32 + slot];
        r.x += e.x; r.y += e.y; r.z += e.z; r.w += e.w;
    }
    ((float4*)tbl)[id * 32 + slot] = r;
}

__global__ __launch_bounds__(256) void relpos_tbl(
    const int*   __restrict__ asym_id,
    const int*   __restrict__ residue_index,
    const int*   __restrict__ entity_id,
    const int*   __restrict__ token_index,
    const int*   __restrict__ sym_id,
    const float* __restrict__ tbl,    // 270 x 128 f32 combined rows
    float*       __restrict__ out)    // 1024 x 1024 x 128 f32
{
    __shared__ int s_id[64];

    const int tid = threadIdx.x;
    const int i   = blockIdx.x >> 4;          // 16 blocks per i-row
    const int j0  = (blockIdx.x & 15) << 6;   // 64 j's per block

    if (tid < 64) {
        const int j  = j0 + tid;
        const int ai = asym_id[i],       aj = asym_id[j];
        const int ri = residue_index[i], rj = residue_index[j];
        const int ti = token_index[i],   tj = token_index[j];
        const int si = sym_id[i],        sj = sym_id[j];
        const int ei = entity_id[i],     ej = entity_id[j];

        int base;
        if (ai != aj) {                                   // !same_chain
            base = min(max(si - sj + S_MAX, 0), 2 * S_MAX);        // 0..4
        } else if (ri != rj) {                            // same_chain & !same_res
            base = 5 + min(max(ri - rj + R_MAX, 0), 2 * R_MAX);    // 5..69
        } else {                                          // same_chain & same_res
            base = 70 + min(max(ti - tj + R_MAX, 0), 2 * R_MAX);   // 70..134
        }
        s_id[tid] = base + ((ei == ej) ? TBL_BASE : 0);
    }
    __syncthreads();

    const int slot    = tid & 31;   // fixed float4 channel slot per thread
    const int plocal0 = tid >> 5;   // 0..7

    const float4* __restrict__ T4 = (const float4*)tbl;
    float4* __restrict__ outp = (float4*)out + ((long long)blockIdx.x << 11);

    #pragma unroll
    for (int iter = 0; iter < 8; ++iter) {
        const int pl = plocal0 + iter * 8;            // pair-local index 0..63
        const int id = s_id[pl];
        outp[pl * 32 + slot] = T4[id * 32 + slot];
    }
}

// Fallback (R1 kernel) if workspace is too small for the table.
__global__ __launch_bounds__(256) void relpos_direct(
    const int*   __restrict__ asym_id,
    const int*   __restrict__ residue_index,
    const int*   __restrict__ entity_id,
    const int*   __restrict__ token_index,
    const int*   __restrict__ sym_id,
    const float* __restrict__ W,
    float*       __restrict__ out)
{
    __shared__ int s_idx[64];
    const int tid = threadIdx.x;
    const int i   = blockIdx.x >> 4;
    const int j0  = (blockIdx.x & 15) << 6;

    if (tid < 64) {
        const int j  = j0 + tid;
        const int ai = asym_id[i],       aj = asym_id[j];
        const int ri = residue_index[i], rj = residue_index[j];
        const int ti = token_index[i],   tj = token_index[j];
        const int si = sym_id[i],        sj = sym_id[j];
        const int ei = entity_id[i],     ej = entity_id[j];
        const bool same_chain = (ai == aj);
        const bool same_res   = (ri == rj);
        int d_res = min(max(ri - rj + R_MAX, 0), 2 * R_MAX);
        if (!same_chain) d_res = 2 * R_MAX + 1;
        int d_tok = min(max(ti - tj + R_MAX, 0), 2 * R_MAX);
        if (!(same_chain && same_res)) d_tok = 2 * R_MAX + 1;
        const int d_chain = same_chain ? (2 * S_MAX + 1)
                                       : min(max(si - sj + S_MAX, 0), 2 * S_MAX);
        const int ent = (ei == ej) ? 1 : 0;
        s_idx[tid] = d_res | (d_tok << 7) | (d_chain << 14) | (ent << 17);
    }
    __syncthreads();

    const int slot    = tid & 31;
    const int plocal0 = tid >> 5;
    const float4* __restrict__ W4 = (const float4*)W;
    const float4 e = W4[ROW_ENT * 32 + slot];
    float4* __restrict__ outp = (float4*)out + ((long long)blockIdx.x << 11);

    #pragma unroll
    for (int iter = 0; iter < 8; ++iter) {
        const int pl      = plocal0 + iter * 8;
        const int packed  = s_idx[pl];
        const int d_res   =  packed        & 127;
        const int d_tok   = (packed >> 7)  & 127;
        const int d_chain = (packed >> 14) & 7;
        const float m     = (packed & (1 << 17)) ? 1.0f : 0.0f;
        const float4 a = W4[(ROW_POS   + d_res)   * 32 + slot];
        const float4 b = W4[(ROW_TOK   + d_tok)   * 32 + slot];
        const float4 c = W4[(ROW_CHAIN + d_chain) * 32 + slot];
        float4 r;
        r.x = a.x + b.x + c.x + m * e.x;
        r.y = a.y + b.y + c.y + m * e.y;
        r.z = a.z + b.z + c.z + m * e.z;
        r.w = a.w + b.w + c.w + m * e.w;
        outp[pl * 32 + slot] = r;
    }
}

extern "C" void kernel_launch(void* const* d_in, const int* in_sizes, int n_in,
                              void* d_out, int out_size, void* d_ws, size_t ws_size,
                              hipStream_t stream) {
    const int*   asym_id       = (const int*)d_in[0];
    const int*   residue_index = (const int*)d_in[1];
    const int*   entity_id     = (const int*)d_in[2];
    const int*   token_index   = (const int*)d_in[3];
    const int*   sym_id        = (const int*)d_in[4];
    const float* W             = (const float*)d_in[5];
    float*       out           = (float*)d_out;

    const int grid  = (N_TOK * N_TOK) / 64;   // 16384 blocks, 64 pairs each
    const int block = 256;

    if (ws_size >= (size_t)TBL_BYTES) {
        float* tbl = (float*)d_ws;
        build_table<<<(TBL_ROWS * 32 + 255) / 256, 256, 0, stream>>>(W, tbl);
        relpos_tbl<<<grid, block, 0, stream>>>(
            asym_id, residue_index, entity_id, token_index, sym_id, tbl, out);
    } else {
        relpos_direct<<<grid, block, 0, stream>>>(
            asym_id, residue_index, entity_id, token_index, sym_id, W, out);
    }
}

// Round 4
// 105.353 us; speedup vs baseline: 1.0453x; 1.0453x over previous
//
#include <hip/hip_runtime.h>

// RelativePositionEncoder: out[i,j,:] = W_pos[d_res] + W_tok[d_tok]
//                                      + W_chain[d_chain] + same_entity * w_ent
// B=1, N=1024, TOKEN_Z=128, W is 139x128 f32 (66 pos + 66 tok + 1 ent + 6 chain).
//
// Write-BW-bound (537 MB out; W is cache-resident; floor ~79 us at the
// fill-kernel's 6.8 TB/s). R3: persistent blocks (2048 = 8/CU, 32 waves/CU),
// each owns 8 tiles of 64 pairs; bin indices double-buffered in LDS so tile
// t+1's index math overlaps tile t's stores; one barrier per tile.

#define N_TOK   1024
#define R_MAX   32
#define S_MAX   2
#define ROW_POS   0
#define ROW_TOK   66
#define ROW_ENT   132
#define ROW_CHAIN 133

#define TILES_PER_BLOCK 8
#define NUM_BLOCKS ((N_TOK * N_TOK / 64) / TILES_PER_BLOCK)   // 2048

__device__ __forceinline__ int pack_idx(
    const int* __restrict__ asym_id, const int* __restrict__ residue_index,
    const int* __restrict__ entity_id, const int* __restrict__ token_index,
    const int* __restrict__ sym_id, int i, int j)
{
    const int ai = asym_id[i],       aj = asym_id[j];
    const int ri = residue_index[i], rj = residue_index[j];
    const int ti = token_index[i],   tj = token_index[j];
    const int si = sym_id[i],        sj = sym_id[j];
    const int ei = entity_id[i],     ej = entity_id[j];

    const bool same_chain = (ai == aj);
    const bool same_res   = (ri == rj);

    int d_res = min(max(ri - rj + R_MAX, 0), 2 * R_MAX);
    if (!same_chain) d_res = 2 * R_MAX + 1;

    int d_tok = min(max(ti - tj + R_MAX, 0), 2 * R_MAX);
    if (!(same_chain && same_res)) d_tok = 2 * R_MAX + 1;

    const int d_chain = same_chain ? (2 * S_MAX + 1)
                                   : min(max(si - sj + S_MAX, 0), 2 * S_MAX);
    const int ent = (ei == ej) ? 1 : 0;

    return d_res | (d_tok << 7) | (d_chain << 14) | (ent << 17);
}

__global__ __launch_bounds__(256) void relpos_kernel(
    const int*   __restrict__ asym_id,
    const int*   __restrict__ residue_index,
    const int*   __restrict__ entity_id,
    const int*   __restrict__ token_index,
    const int*   __restrict__ sym_id,
    const float* __restrict__ W,      // 139 x 128 row-major f32
    float*       __restrict__ out)    // 1024 x 1024 x 128 f32
{
    __shared__ int s_id[2][64];

    const int tid   = threadIdx.x;
    const int tile0 = blockIdx.x * TILES_PER_BLOCK;

    // Prime buffer 0 with tile 0's indices.
    if (tid < 64) {
        const int tile = tile0;
        const int i  = tile >> 4;
        const int j  = ((tile & 15) << 6) + tid;
        s_id[0][tid] = pack_idx(asym_id, residue_index, entity_id,
                                token_index, sym_id, i, j);
    }
    __syncthreads();

    const int slot    = tid & 31;   // fixed float4 channel slot per thread
    const int plocal0 = tid >> 5;   // 0..7

    const float4* __restrict__ W4 = (const float4*)W;  // 139 rows x 32 float4
    const float4 e = W4[ROW_ENT * 32 + slot];          // invariant

    for (int t = 0; t < TILES_PER_BLOCK; ++t) {
        const int buf = t & 1;

        // Overlap: compute next tile's indices into the other buffer.
        if (t + 1 < TILES_PER_BLOCK && tid < 64) {
            const int tile = tile0 + t + 1;
            const int i  = tile >> 4;
            const int j  = ((tile & 15) << 6) + tid;
            s_id[buf ^ 1][tid] = pack_idx(asym_id, residue_index, entity_id,
                                          token_index, sym_id, i, j);
        }

        float4* __restrict__ outp =
            (float4*)out + ((long long)(tile0 + t) << 11);

        #pragma unroll
        for (int iter = 0; iter < 8; ++iter) {
            const int pl      = plocal0 + iter * 8;      // pair-local 0..63
            const int packed  = s_id[buf][pl];
            const int d_res   =  packed        & 127;
            const int d_tok   = (packed >> 7)  & 127;
            const int d_chain = (packed >> 14) & 7;
            const float m     = (packed & (1 << 17)) ? 1.0f : 0.0f;

            const float4 a = W4[(ROW_POS   + d_res)   * 32 + slot];
            const float4 b = W4[(ROW_TOK   + d_tok)   * 32 + slot];
            const float4 c = W4[(ROW_CHAIN + d_chain) * 32 + slot];

            float4 r;
            r.x = a.x + b.x + c.x + m * e.x;
            r.y = a.y + b.y + c.y + m * e.y;
            r.z = a.z + b.z + c.z + m * e.z;
            r.w = a.w + b.w + c.w + m * e.w;

            outp[pl * 32 + slot] = r;
        }

        __syncthreads();   // buf[t&1] free for reuse; buf^1 now valid
    }
}

extern "C" void kernel_launch(void* const* d_in, const int* in_sizes, int n_in,
                              void* d_out, int out_size, void* d_ws, size_t ws_size,
                              hipStream_t stream) {
    const int*   asym_id       = (const int*)d_in[0];
    const int*   residue_index = (const int*)d_in[1];
    const int*   entity_id     = (const int*)d_in[2];
    const int*   token_index   = (const int*)d_in[3];
    const int*   sym_id        = (const int*)d_in[4];
    const float* W             = (const float*)d_in[5];
    float*       out           = (float*)d_out;

    relpos_kernel<<<NUM_BLOCKS, 256, 0, stream>>>(
        asym_id, residue_index, entity_id, token_index, sym_id, W, out);
}